// Round 3
// baseline (144.883 us; speedup 1.0000x reference)
//
#include <hip/hip_runtime.h>
#include <math.h>

#define NPTS   2048
#define BD1    256
#define CH     8              // chunks per batch in phase 1 (NPTS/CH == BD1)
#define NMOM   72
#define NITERS 10
#define DAMPF  1e-8f

// ---------------------------------------------------------------------------
// Phase 1: per-batch iteration-independent moments, split into CH chunks.
// One point per thread; two-fold shuffle reduction; partials to ws.
// Moment layout (same as R2):
//   0..5   : SW[ij]      = sum W_ij              (sym idx 00,01,02,11,12,22)
//   6..23  : A1[ij][c]   = sum W_ij * s_c        (6+ij*3+c)
//   24..59 : A2[ij][cd]  = sum W_ij * s_c*s_d    (24+ij*6+cd)
//   60..62 : b0[i]       = sum (W g)_i
//   63..71 : B1[c][i]    = sum s_c * (W g)_i     (63+c*3+i)
// Partial store: mom[(k*CH + c)*B + b]  (coalesced over b in phase 2)
// ---------------------------------------------------------------------------
__launch_bounds__(BD1, 4)
__global__ void moments_kernel(const float* __restrict__ src4,
                               const float* __restrict__ trg4,
                               const float* __restrict__ wts,
                               const float* __restrict__ icov,
                               float* __restrict__ mom, int B)
{
    const int bc   = blockIdx.x;
    const int b    = bc >> 3;          // CH == 8
    const int c    = bc & 7;
    const int tid  = threadIdx.x;
    const int lane = tid & 63;
    const int wid  = tid >> 6;
    const int n    = c * BD1 + tid;    // point index within batch

    const float* srcb = src4 + (size_t)b * 4 * NPTS;
    const float* trgb = trg4 + (size_t)b * 4 * NPTS;

    float sx = srcb[n], sy = srcb[NPTS + n], sz = srcb[2 * NPTS + n];
    float gx = trgb[n], gy = trgb[NPTS + n], gz = trgb[2 * NPTS + n];
    float w  = wts[(size_t)b * NPTS + n];
    const float* cc = icov + ((size_t)b * NPTS + n) * 9;
    float w2 = 2.0f * w * w;
    float W[6];
    W[0] = w2 * cc[0];   // xx
    W[1] = w2 * cc[3];   // xy (lower tri, matching chol's reads)
    W[2] = w2 * cc[6];   // xz
    W[3] = w2 * cc[4];   // yy
    W[4] = w2 * cc[7];   // yz
    W[5] = w2 * cc[8];   // zz

    float hx = W[0] * gx + W[1] * gy + W[2] * gz;
    float hy = W[1] * gx + W[3] * gy + W[4] * gz;
    float hz = W[2] * gx + W[4] * gy + W[5] * gz;

    float sv[3] = { sx, sy, sz };
    float hv[3] = { hx, hy, hz };
    float ss[6] = { sx*sx, sx*sy, sx*sz, sy*sy, sy*sz, sz*sz };

    float acc[NMOM];
    #pragma unroll
    for (int ij = 0; ij < 6; ++ij) {
        acc[ij] = W[ij];
        #pragma unroll
        for (int c2 = 0; c2 < 3; ++c2) acc[6 + ij * 3 + c2] = W[ij] * sv[c2];
        #pragma unroll
        for (int cd = 0; cd < 6; ++cd) acc[24 + ij * 6 + cd] = W[ij] * ss[cd];
    }
    acc[60] = hx; acc[61] = hy; acc[62] = hz;
    #pragma unroll
    for (int c2 = 0; c2 < 3; ++c2)
        #pragma unroll
        for (int i = 0; i < 3; ++i) acc[63 + c2 * 3 + i] = sv[c2] * hv[i];

    // ---- fold 1: 64->32 lanes, 72->36 values per lane ----
    // lanes<32 keep accs [0..35], lanes>=32 keep accs [36..71]
    float v36[36];
    #pragma unroll
    for (int k = 0; k < 36; ++k) {
        float lo  = acc[k],  hi  = acc[k + 36];
        float lox = __shfl_xor(lo, 32, 64);
        float hix = __shfl_xor(hi, 32, 64);
        v36[k] = (lane & 32) ? (hi + hix) : (lo + lox);
    }
    // ---- fold 2: 32->16 lanes, 36->18 values ----
    // 16-lane group q = lane>>4 holds accs [q*18 .. q*18+17]
    float v18[18];
    #pragma unroll
    for (int k = 0; k < 18; ++k) {
        float lo  = v36[k],  hi  = v36[k + 18];
        float lox = __shfl_xor(lo, 16, 64);
        float hix = __shfl_xor(hi, 16, 64);
        v18[k] = (lane & 16) ? (hi + hix) : (lo + lox);
    }
    // ---- butterfly over remaining 16 lanes ----
    #pragma unroll
    for (int k = 0; k < 18; ++k) {
        float v = v18[k];
        v += __shfl_xor(v, 8, 64);
        v += __shfl_xor(v, 4, 64);
        v += __shfl_xor(v, 2, 64);
        v += __shfl_xor(v, 1, 64);
        v18[k] = v;
    }

    __shared__ float red[BD1 / 64][NMOM];
    if ((lane & 15) == 0) {
        int q = lane >> 4;
        #pragma unroll
        for (int k = 0; k < 18; ++k) red[wid][q * 18 + k] = v18[k];
    }
    __syncthreads();

    if (tid < NMOM) {
        float s = red[0][tid] + red[1][tid] + red[2][tid] + red[3][tid];
        mom[((size_t)tid * CH + c) * B + b] = s;
    }
}

// ---------------------------------------------------------------------------
// Phase 2: one thread per batch. 10 GN iterations assembled from moments.
// ---------------------------------------------------------------------------
__launch_bounds__(64, 1)
__global__ void solve_kernel(const float* __restrict__ mom,
                             const float* __restrict__ Tinit,
                             const float* __restrict__ Tsv,
                             float* __restrict__ out, int B)
{
    const int b = blockIdx.x * 64 + threadIdx.x;
    if (b >= B) return;

    float m[NMOM];
    #pragma unroll
    for (int k = 0; k < NMOM; ++k) {
        float s = 0.0f;
        #pragma unroll
        for (int c = 0; c < CH; ++c) s += mom[((size_t)k * CH + c) * B + b];
        m[k] = s;
    }

    float Rm[3][3], tv[3];
    #pragma unroll
    for (int i = 0; i < 3; ++i) {
        #pragma unroll
        for (int j = 0; j < 3; ++j) Rm[i][j] = Tinit[b * 16 + i * 4 + j];
        tv[i] = Tinit[b * 16 + i * 4 + 3];
    }

    const int SY[3][3] = { {0,1,2}, {1,3,4}, {2,4,5} };

    for (int it = 0; it < NITERS; ++it) {
        // C1[ij][a] = sum W_ij * p_a  (p = R s)
        float C1[6][3];
        #pragma unroll
        for (int ij = 0; ij < 6; ++ij) {
            float a0 = m[6 + ij * 3 + 0], a1 = m[6 + ij * 3 + 1], a2 = m[6 + ij * 3 + 2];
            #pragma unroll
            for (int a = 0; a < 3; ++a)
                C1[ij][a] = Rm[a][0] * a0 + Rm[a][1] * a1 + Rm[a][2] * a2;
        }
        float SM[3][3], SWp[3];
        #pragma unroll
        for (int i = 0; i < 3; ++i) {
            SM[i][0] = C1[SY[i][1]][2] - C1[SY[i][2]][1];
            SM[i][1] = C1[SY[i][2]][0] - C1[SY[i][0]][2];
            SM[i][2] = C1[SY[i][0]][1] - C1[SY[i][1]][0];
            SWp[i]   = C1[SY[i][0]][0] + C1[SY[i][1]][1] + C1[SY[i][2]][2];
        }
        // P2[ab][ij] = sum p_a p_b W_ij = (R A2[ij] R^T)_{ab}
        float P2[6][6];
        #pragma unroll
        for (int ij = 0; ij < 6; ++ij) {
            float S00 = m[24 + ij * 6 + 0], S01 = m[24 + ij * 6 + 1], S02 = m[24 + ij * 6 + 2];
            float S11 = m[24 + ij * 6 + 3], S12 = m[24 + ij * 6 + 4], S22 = m[24 + ij * 6 + 5];
            float U[3][3];
            #pragma unroll
            for (int a = 0; a < 3; ++a) {
                U[a][0] = Rm[a][0] * S00 + Rm[a][1] * S01 + Rm[a][2] * S02;
                U[a][1] = Rm[a][0] * S01 + Rm[a][1] * S11 + Rm[a][2] * S12;
                U[a][2] = Rm[a][0] * S02 + Rm[a][1] * S12 + Rm[a][2] * S22;
            }
            P2[0][ij] = U[0][0]*Rm[0][0] + U[0][1]*Rm[0][1] + U[0][2]*Rm[0][2];
            P2[1][ij] = U[0][0]*Rm[1][0] + U[0][1]*Rm[1][1] + U[0][2]*Rm[1][2];
            P2[2][ij] = U[0][0]*Rm[2][0] + U[0][1]*Rm[2][1] + U[0][2]*Rm[2][2];
            P2[3][ij] = U[1][0]*Rm[1][0] + U[1][1]*Rm[1][1] + U[1][2]*Rm[1][2];
            P2[4][ij] = U[1][0]*Rm[2][0] + U[1][1]*Rm[2][1] + U[1][2]*Rm[2][2];
            P2[5][ij] = U[2][0]*Rm[2][0] + U[2][1]*Rm[2][1] + U[2][2]*Rm[2][2];
        }
        float SN00 = -P2[5][3] + 2.f * P2[4][4] - P2[3][5];
        float SN01 = -P2[2][4] + P2[5][1] + P2[1][5] - P2[4][2];
        float SN02 = -P2[4][1] + P2[2][3] + P2[3][2] - P2[1][4];
        float SN11 =  2.f * P2[2][2] - P2[5][0] - P2[0][5];
        float SN12 =  P2[4][0] - P2[2][1] - P2[1][2] + P2[0][4];
        float SN22 = -P2[3][0] + 2.f * P2[1][1] - P2[0][3];

        float SWt0 = m[0]*tv[0] + m[1]*tv[1] + m[2]*tv[2];
        float SWt1 = m[1]*tv[0] + m[3]*tv[1] + m[4]*tv[2];
        float SWt2 = m[2]*tv[0] + m[4]*tv[1] + m[5]*tv[2];
        float Su[3] = { m[60] - SWp[0] - SWt0,
                        m[61] - SWp[1] - SWt1,
                        m[62] - SWp[2] - SWt2 };

        float G[3][3];
        #pragma unroll
        for (int a = 0; a < 3; ++a)
            #pragma unroll
            for (int bb = 0; bb < 3; ++bb)
                G[a][bb] = Rm[a][0]*m[63 + 0 + bb] + Rm[a][1]*m[63 + 3 + bb] + Rm[a][2]*m[63 + 6 + bb];
        float ch[3] = { G[1][2] - G[2][1], G[2][0] - G[0][2], G[0][1] - G[1][0] };
        float pw[3];
        pw[0] = P2[1][2] + P2[3][4] + P2[4][5] - P2[2][1] - P2[4][3] - P2[5][4];
        pw[1] = P2[2][0] + P2[4][1] + P2[5][2] - P2[0][2] - P2[1][4] - P2[2][5];
        pw[2] = P2[0][1] + P2[1][3] + P2[2][4] - P2[1][0] - P2[3][1] - P2[4][2];
        float Sq[3];
        #pragma unroll
        for (int i = 0; i < 3; ++i)
            Sq[i] = ch[i] - pw[i] + SM[0][i]*tv[0] + SM[1][i]*tv[1] + SM[2][i]*tv[2];

        float Hm[6][6];
        Hm[0][0] = m[0]; Hm[0][1] = m[1]; Hm[0][2] = m[2];
        Hm[1][1] = m[3]; Hm[1][2] = m[4]; Hm[2][2] = m[5];
        #pragma unroll
        for (int i = 0; i < 3; ++i) {
            Hm[i][3] = -SM[i][0]; Hm[i][4] = -SM[i][1]; Hm[i][5] = -SM[i][2];
        }
        Hm[3][3] = -SN00; Hm[3][4] = -SN01; Hm[3][5] = -SN02;
        Hm[4][4] = -SN11; Hm[4][5] = -SN12; Hm[5][5] = -SN22;
        #pragma unroll
        for (int i = 0; i < 6; ++i) {
            Hm[i][i] += DAMPF;
            #pragma unroll
            for (int j = 0; j < 6; ++j)
                if (j < i) Hm[i][j] = Hm[j][i];
        }
        float rhs[6] = { Su[0], Su[1], Su[2], Sq[0], Sq[1], Sq[2] };

        // Cholesky with reciprocal diagonal (6 divides total)
        float L[6][6], dinv[6];
        #pragma unroll
        for (int i = 0; i < 6; ++i) {
            #pragma unroll
            for (int j = 0; j < 6; ++j) {
                if (j > i) continue;
                float sum = Hm[i][j];
                #pragma unroll
                for (int k2 = 0; k2 < 6; ++k2)
                    if (k2 < j) sum -= L[i][k2] * L[j][k2];
                if (i == j) { L[i][i] = sqrtf(sum); dinv[i] = 1.0f / L[i][i]; }
                else        L[i][j] = sum * dinv[j];
            }
        }
        float z[6];
        #pragma unroll
        for (int i = 0; i < 6; ++i) {
            float sum = rhs[i];
            #pragma unroll
            for (int k2 = 0; k2 < 6; ++k2)
                if (k2 < i) sum -= L[i][k2] * z[k2];
            z[i] = sum * dinv[i];
        }
        float y[6];
        #pragma unroll
        for (int i = 5; i >= 0; --i) {
            float sum = z[i];
            #pragma unroll
            for (int k2 = 0; k2 < 6; ++k2)
                if (k2 > i) sum -= L[k2][i] * y[k2];
            y[i] = sum * dinv[i];
        }

        float drx = Rm[0][0]*y[0] + Rm[1][0]*y[1] + Rm[2][0]*y[2];
        float dry = Rm[0][1]*y[0] + Rm[1][1]*y[1] + Rm[2][1]*y[2];
        float drz = Rm[0][2]*y[0] + Rm[1][2]*y[1] + Rm[2][2]*y[2];
        float dpx = Rm[0][0]*y[3] + Rm[1][0]*y[4] + Rm[2][0]*y[5];
        float dpy = Rm[0][1]*y[3] + Rm[1][1]*y[4] + Rm[2][1]*y[5];
        float dpz = Rm[0][2]*y[3] + Rm[1][2]*y[4] + Rm[2][2]*y[5];

        float th2  = dpx*dpx + dpy*dpy + dpz*dpz;
        bool  sm   = th2 < 1e-12f;
        float th2s = sm ? 1.0f : th2;
        float th   = sqrtf(th2s);
        float sth  = __sinf(th), cth = __cosf(th);
        float it2  = 1.0f / th2s;
        float Ae = sm ? 1.0f : sth / th;
        float Be = sm ? 0.5f : (1.0f - cth) * it2;
        float Ce = sm ? (1.0f / 6.0f) : (th - sth) * it2 / th;
        float Rd00 = 1.0f + Be * (dpx*dpx - th2);
        float Rd01 = -Ae * dpz + Be * dpx * dpy;
        float Rd02 =  Ae * dpy + Be * dpx * dpz;
        float Rd10 =  Ae * dpz + Be * dpx * dpy;
        float Rd11 = 1.0f + Be * (dpy*dpy - th2);
        float Rd12 = -Ae * dpx + Be * dpy * dpz;
        float Rd20 = -Ae * dpy + Be * dpx * dpz;
        float Rd21 =  Ae * dpx + Be * dpy * dpz;
        float Rd22 = 1.0f + Be * (dpz*dpz - th2);
        float V00 = 1.0f + Ce * (dpx*dpx - th2);
        float V01 = -Be * dpz + Ce * dpx * dpy;
        float V02 =  Be * dpy + Ce * dpx * dpz;
        float V10 =  Be * dpz + Ce * dpx * dpy;
        float V11 = 1.0f + Ce * (dpy*dpy - th2);
        float V12 = -Be * dpx + Ce * dpy * dpz;
        float V20 = -Be * dpy + Ce * dpx * dpz;
        float V21 =  Be * dpx + Ce * dpy * dpz;
        float V22 = 1.0f + Ce * (dpz*dpz - th2);
        float tdx = V00 * drx + V01 * dry + V02 * drz;
        float tdy = V10 * drx + V11 * dry + V12 * drz;
        float tdz = V20 * drx + V21 * dry + V22 * drz;

        float nR[3][3];
        nR[0][0] = Rm[0][0]*Rd00 + Rm[0][1]*Rd10 + Rm[0][2]*Rd20;
        nR[0][1] = Rm[0][0]*Rd01 + Rm[0][1]*Rd11 + Rm[0][2]*Rd21;
        nR[0][2] = Rm[0][0]*Rd02 + Rm[0][1]*Rd12 + Rm[0][2]*Rd22;
        nR[1][0] = Rm[1][0]*Rd00 + Rm[1][1]*Rd10 + Rm[1][2]*Rd20;
        nR[1][1] = Rm[1][0]*Rd01 + Rm[1][1]*Rd11 + Rm[1][2]*Rd21;
        nR[1][2] = Rm[1][0]*Rd02 + Rm[1][1]*Rd12 + Rm[1][2]*Rd22;
        nR[2][0] = Rm[2][0]*Rd00 + Rm[2][1]*Rd10 + Rm[2][2]*Rd20;
        nR[2][1] = Rm[2][0]*Rd01 + Rm[2][1]*Rd11 + Rm[2][2]*Rd21;
        nR[2][2] = Rm[2][0]*Rd02 + Rm[2][1]*Rd12 + Rm[2][2]*Rd22;
        float ntx = Rm[0][0]*tdx + Rm[0][1]*tdy + Rm[0][2]*tdz + tv[0];
        float nty = Rm[1][0]*tdx + Rm[1][1]*tdy + Rm[1][2]*tdz + tv[1];
        float ntz = Rm[2][0]*tdx + Rm[2][1]*tdy + Rm[2][2]*tdz + tv[2];
        #pragma unroll
        for (int i = 0; i < 3; ++i)
            #pragma unroll
            for (int j = 0; j < 3; ++j) Rm[i][j] = nR[i][j];
        tv[0] = ntx; tv[1] = nty; tv[2] = ntz;
    }

    // epilogue: Out = inv(Tsv) * T * Tsv
    {
        float R00 = Rm[0][0], R01 = Rm[0][1], R02 = Rm[0][2];
        float R10 = Rm[1][0], R11 = Rm[1][1], R12 = Rm[1][2];
        float R20 = Rm[2][0], R21 = Rm[2][1], R22 = Rm[2][2];
        float tx = tv[0], ty = tv[1], tz = tv[2];

        float Rv00 = Tsv[0], Rv01 = Tsv[1], Rv02 = Tsv[2],  tvx = Tsv[3];
        float Rv10 = Tsv[4], Rv11 = Tsv[5], Rv12 = Tsv[6],  tvy = Tsv[7];
        float Rv20 = Tsv[8], Rv21 = Tsv[9], Rv22 = Tsv[10], tvz = Tsv[11];

        float P00 = R00*Rv00 + R01*Rv10 + R02*Rv20;
        float P01 = R00*Rv01 + R01*Rv11 + R02*Rv21;
        float P02 = R00*Rv02 + R01*Rv12 + R02*Rv22;
        float P10 = R10*Rv00 + R11*Rv10 + R12*Rv20;
        float P11 = R10*Rv01 + R11*Rv11 + R12*Rv21;
        float P12 = R10*Rv02 + R11*Rv12 + R12*Rv22;
        float P20 = R20*Rv00 + R21*Rv10 + R22*Rv20;
        float P21 = R20*Rv01 + R21*Rv11 + R22*Rv21;
        float P22 = R20*Rv02 + R21*Rv12 + R22*Rv22;
        float Ptx = R00*tvx + R01*tvy + R02*tvz + tx;
        float Pty = R10*tvx + R11*tvy + R12*tvz + ty;
        float Ptz = R20*tvx + R21*tvy + R22*tvz + tz;

        float ex = Ptx - tvx, ey = Pty - tvy, ez = Ptz - tvz;
        float* o = out + (size_t)b * 16;
        o[0]  = Rv00*P00 + Rv10*P10 + Rv20*P20;
        o[1]  = Rv00*P01 + Rv10*P11 + Rv20*P21;
        o[2]  = Rv00*P02 + Rv10*P12 + Rv20*P22;
        o[3]  = Rv00*ex  + Rv10*ey  + Rv20*ez;
        o[4]  = Rv01*P00 + Rv11*P10 + Rv21*P20;
        o[5]  = Rv01*P01 + Rv11*P11 + Rv21*P21;
        o[6]  = Rv01*P02 + Rv11*P12 + Rv21*P21 + (Rv11*P11 - Rv11*P11); // placeholder removed below
        o[6]  = Rv01*P02 + Rv11*P12 + Rv21*P22;
        o[7]  = Rv01*ex  + Rv11*ey  + Rv21*ez;
        o[8]  = Rv02*P00 + Rv12*P10 + Rv22*P20;
        o[9]  = Rv02*P01 + Rv12*P11 + Rv22*P21;
        o[10] = Rv02*P02 + Rv12*P12 + Rv22*P22;
        o[11] = Rv02*ex  + Rv12*ey  + Rv22*ez;
        o[12] = 0.0f; o[13] = 0.0f; o[14] = 0.0f; o[15] = 1.0f;
    }
}

extern "C" void kernel_launch(void* const* d_in, const int* in_sizes, int n_in,
                              void* d_out, int out_size, void* d_ws, size_t ws_size,
                              hipStream_t stream)
{
    const float* src4  = (const float*)d_in[0];
    const float* trg4  = (const float*)d_in[1];
    const float* wts   = (const float*)d_in[2];
    const float* Tinit = (const float*)d_in[3];
    const float* icov  = (const float*)d_in[4];
    const float* Tsv   = (const float*)d_in[5];

    const int B = in_sizes[3] / 16;   // T_trg_src_init is (B,4,4)
    float* mom = (float*)d_ws;        // 72*CH*B floats of partial moments

    hipLaunchKernelGGL(moments_kernel, dim3(B * CH), dim3(BD1), 0, stream,
                       src4, trg4, wts, icov, mom, B);
    hipLaunchKernelGGL(solve_kernel, dim3((B + 63) / 64), dim3(64), 0, stream,
                       mom, Tinit, Tsv, (float*)d_out, B);
}

// Round 4
// 114.343 us; speedup vs baseline: 1.2671x; 1.2671x over previous
//
#include <hip/hip_runtime.h>
#include <math.h>

#define NPTS   2048
#define BDIM   512
#define PPT    (NPTS / BDIM)   // 4 points per thread
#define NW     (BDIM / 64)     // 8 waves per block
#define NMOM   72
#define NITERS 10
#define DAMPF  1e-8f

// One block per batch. Phase A: 72 iteration-independent moments -> LDS.
// Phase B: wave 0 runs the 10 GN iterations from LDS-resident moments.
// Moment layout:
//   0..5   : SW[ij]      = sum W_ij              (sym idx 00,01,02,11,12,22)
//   6..23  : A1[ij][c]   = sum W_ij * s_c        (6+ij*3+c)
//   24..59 : A2[ij][cd]  = sum W_ij * s_c*s_d    (24+ij*6+cd)
//   60..62 : b0[i]       = sum (W g)_i
//   63..71 : B1[c][i]    = sum s_c * (W g)_i     (63+c*3+i)
__launch_bounds__(BDIM, 1)
__global__ void lie_gn_fused(const float* __restrict__ src4,
                             const float* __restrict__ trg4,
                             const float* __restrict__ wts,
                             const float* __restrict__ Tinit,
                             const float* __restrict__ icov,
                             const float* __restrict__ Tsv,
                             float* __restrict__ out)
{
    const int b    = blockIdx.x;
    const int tid  = threadIdx.x;
    const int lane = tid & 63;
    const int wid  = tid >> 6;

    __shared__ float red[NW][NMOM];
    __shared__ float mom_s[NMOM];

    const float* srcb = src4 + (size_t)b * 4 * NPTS;
    const float* trgb = trg4 + (size_t)b * 4 * NPTS;
    const float* wb   = wts  + (size_t)b * NPTS;
    const float* cb   = icov + (size_t)b * NPTS * 9;

    // ---------------- phase A: moments ----------------
    float acc[NMOM];
    #pragma unroll
    for (int k = 0; k < NMOM; ++k) acc[k] = 0.0f;

    #pragma unroll
    for (int kk = 0; kk < PPT; ++kk) {
        int n = tid + kk * BDIM;
        float sx = srcb[n], sy = srcb[NPTS + n], sz = srcb[2 * NPTS + n];
        float gx = trgb[n], gy = trgb[NPTS + n], gz = trgb[2 * NPTS + n];
        float w  = wb[n];
        const float* cc = cb + (size_t)n * 9;
        float w2 = 2.0f * w * w;
        float W[6];
        W[0] = w2 * cc[0];   // xx
        W[1] = w2 * cc[3];   // xy (lower tri, matching chol's reads)
        W[2] = w2 * cc[6];   // xz
        W[3] = w2 * cc[4];   // yy
        W[4] = w2 * cc[7];   // yz
        W[5] = w2 * cc[8];   // zz

        float hx = W[0] * gx + W[1] * gy + W[2] * gz;
        float hy = W[1] * gx + W[3] * gy + W[4] * gz;
        float hz = W[2] * gx + W[4] * gy + W[5] * gz;

        float sv[3] = { sx, sy, sz };
        float hv[3] = { hx, hy, hz };
        float ss[6] = { sx*sx, sx*sy, sx*sz, sy*sy, sy*sz, sz*sz };

        #pragma unroll
        for (int ij = 0; ij < 6; ++ij) {
            acc[ij] += W[ij];
            #pragma unroll
            for (int c2 = 0; c2 < 3; ++c2) acc[6 + ij * 3 + c2] += W[ij] * sv[c2];
            #pragma unroll
            for (int cd = 0; cd < 6; ++cd) acc[24 + ij * 6 + cd] += W[ij] * ss[cd];
        }
        acc[60] += hx; acc[61] += hy; acc[62] += hz;
        #pragma unroll
        for (int c2 = 0; c2 < 3; ++c2)
            #pragma unroll
            for (int i = 0; i < 3; ++i) acc[63 + c2 * 3 + i] += sv[c2] * hv[i];
    }

    // fold 1: 64->32 lanes, 72->36 values (bit5 selects half)
    float v36[36];
    #pragma unroll
    for (int k = 0; k < 36; ++k) {
        float lo  = acc[k],  hi  = acc[k + 36];
        float lox = __shfl_xor(lo, 32, 64);
        float hix = __shfl_xor(hi, 32, 64);
        v36[k] = (lane & 32) ? (hi + hix) : (lo + lox);
    }
    // fold 2: 32->16 lanes, 36->18 values (bit4); group q=lane>>4 holds accs [q*18..q*18+17]
    float v18[18];
    #pragma unroll
    for (int k = 0; k < 18; ++k) {
        float lo  = v36[k],  hi  = v36[k + 18];
        float lox = __shfl_xor(lo, 16, 64);
        float hix = __shfl_xor(hi, 16, 64);
        v18[k] = (lane & 16) ? (hi + hix) : (lo + lox);
    }
    // butterfly within 16-lane groups
    #pragma unroll
    for (int k = 0; k < 18; ++k) {
        float v = v18[k];
        v += __shfl_xor(v, 8, 64);
        v += __shfl_xor(v, 4, 64);
        v += __shfl_xor(v, 2, 64);
        v += __shfl_xor(v, 1, 64);
        v18[k] = v;
    }
    if ((lane & 15) == 0) {
        int q = lane >> 4;
        #pragma unroll
        for (int k = 0; k < 18; ++k) red[wid][q * 18 + k] = v18[k];
    }
    __syncthreads();

    if (tid < NMOM) {
        float s = 0.0f;
        #pragma unroll
        for (int wv = 0; wv < NW; ++wv) s += red[wv][tid];
        mom_s[tid] = s;
    }
    __syncthreads();

    // ---------------- phase B: solve (wave 0 only, redundant lanes) ----------------
    if (tid >= 64) return;

    float m[NMOM];
    #pragma unroll
    for (int k = 0; k < NMOM; ++k) m[k] = mom_s[k];   // LDS broadcast reads

    float Rm[3][3], tv[3];
    #pragma unroll
    for (int i = 0; i < 3; ++i) {
        #pragma unroll
        for (int j = 0; j < 3; ++j) Rm[i][j] = Tinit[b * 16 + i * 4 + j];
        tv[i] = Tinit[b * 16 + i * 4 + 3];
    }

    const int SY[3][3] = { {0,1,2}, {1,3,4}, {2,4,5} };

    for (int it = 0; it < NITERS; ++it) {
        // C1[ij][a] = sum W_ij * p_a  (p = R s)
        float C1[6][3];
        #pragma unroll
        for (int ij = 0; ij < 6; ++ij) {
            float a0 = m[6 + ij * 3 + 0], a1 = m[6 + ij * 3 + 1], a2 = m[6 + ij * 3 + 2];
            #pragma unroll
            for (int a = 0; a < 3; ++a)
                C1[ij][a] = Rm[a][0] * a0 + Rm[a][1] * a1 + Rm[a][2] * a2;
        }
        float SM[3][3], SWp[3];
        #pragma unroll
        for (int i = 0; i < 3; ++i) {
            SM[i][0] = C1[SY[i][1]][2] - C1[SY[i][2]][1];
            SM[i][1] = C1[SY[i][2]][0] - C1[SY[i][0]][2];
            SM[i][2] = C1[SY[i][0]][1] - C1[SY[i][1]][0];
            SWp[i]   = C1[SY[i][0]][0] + C1[SY[i][1]][1] + C1[SY[i][2]][2];
        }
        // P2[ab][ij] = (R A2[ij] R^T)_{ab}
        float P2[6][6];
        #pragma unroll
        for (int ij = 0; ij < 6; ++ij) {
            float S00 = m[24 + ij * 6 + 0], S01 = m[24 + ij * 6 + 1], S02 = m[24 + ij * 6 + 2];
            float S11 = m[24 + ij * 6 + 3], S12 = m[24 + ij * 6 + 4], S22 = m[24 + ij * 6 + 5];
            float U[3][3];
            #pragma unroll
            for (int a = 0; a < 3; ++a) {
                U[a][0] = Rm[a][0] * S00 + Rm[a][1] * S01 + Rm[a][2] * S02;
                U[a][1] = Rm[a][0] * S01 + Rm[a][1] * S11 + Rm[a][2] * S12;
                U[a][2] = Rm[a][0] * S02 + Rm[a][1] * S12 + Rm[a][2] * S22;
            }
            P2[0][ij] = U[0][0]*Rm[0][0] + U[0][1]*Rm[0][1] + U[0][2]*Rm[0][2];
            P2[1][ij] = U[0][0]*Rm[1][0] + U[0][1]*Rm[1][1] + U[0][2]*Rm[1][2];
            P2[2][ij] = U[0][0]*Rm[2][0] + U[0][1]*Rm[2][1] + U[0][2]*Rm[2][2];
            P2[3][ij] = U[1][0]*Rm[1][0] + U[1][1]*Rm[1][1] + U[1][2]*Rm[1][2];
            P2[4][ij] = U[1][0]*Rm[2][0] + U[1][1]*Rm[2][1] + U[1][2]*Rm[2][2];
            P2[5][ij] = U[2][0]*Rm[2][0] + U[2][1]*Rm[2][1] + U[2][2]*Rm[2][2];
        }
        float SN00 = -P2[5][3] + 2.f * P2[4][4] - P2[3][5];
        float SN01 = -P2[2][4] + P2[5][1] + P2[1][5] - P2[4][2];
        float SN02 = -P2[4][1] + P2[2][3] + P2[3][2] - P2[1][4];
        float SN11 =  2.f * P2[2][2] - P2[5][0] - P2[0][5];
        float SN12 =  P2[4][0] - P2[2][1] - P2[1][2] + P2[0][4];
        float SN22 = -P2[3][0] + 2.f * P2[1][1] - P2[0][3];

        float SWt0 = m[0]*tv[0] + m[1]*tv[1] + m[2]*tv[2];
        float SWt1 = m[1]*tv[0] + m[3]*tv[1] + m[4]*tv[2];
        float SWt2 = m[2]*tv[0] + m[4]*tv[1] + m[5]*tv[2];
        float Su[3] = { m[60] - SWp[0] - SWt0,
                        m[61] - SWp[1] - SWt1,
                        m[62] - SWp[2] - SWt2 };

        float G[3][3];
        #pragma unroll
        for (int a = 0; a < 3; ++a)
            #pragma unroll
            for (int bb = 0; bb < 3; ++bb)
                G[a][bb] = Rm[a][0]*m[63 + 0 + bb] + Rm[a][1]*m[63 + 3 + bb] + Rm[a][2]*m[63 + 6 + bb];
        float ch[3] = { G[1][2] - G[2][1], G[2][0] - G[0][2], G[0][1] - G[1][0] };
        float pw[3];
        pw[0] = P2[1][2] + P2[3][4] + P2[4][5] - P2[2][1] - P2[4][3] - P2[5][4];
        pw[1] = P2[2][0] + P2[4][1] + P2[5][2] - P2[0][2] - P2[1][4] - P2[2][5];
        pw[2] = P2[0][1] + P2[1][3] + P2[2][4] - P2[1][0] - P2[3][1] - P2[4][2];
        float Sq[3];
        #pragma unroll
        for (int i = 0; i < 3; ++i)
            Sq[i] = ch[i] - pw[i] + SM[0][i]*tv[0] + SM[1][i]*tv[1] + SM[2][i]*tv[2];

        float Hm[6][6];
        Hm[0][0] = m[0]; Hm[0][1] = m[1]; Hm[0][2] = m[2];
        Hm[1][1] = m[3]; Hm[1][2] = m[4]; Hm[2][2] = m[5];
        #pragma unroll
        for (int i = 0; i < 3; ++i) {
            Hm[i][3] = -SM[i][0]; Hm[i][4] = -SM[i][1]; Hm[i][5] = -SM[i][2];
        }
        Hm[3][3] = -SN00; Hm[3][4] = -SN01; Hm[3][5] = -SN02;
        Hm[4][4] = -SN11; Hm[4][5] = -SN12; Hm[5][5] = -SN22;
        #pragma unroll
        for (int i = 0; i < 6; ++i) {
            Hm[i][i] += DAMPF;
            #pragma unroll
            for (int j = 0; j < 6; ++j)
                if (j < i) Hm[i][j] = Hm[j][i];
        }
        float rhs[6] = { Su[0], Su[1], Su[2], Sq[0], Sq[1], Sq[2] };

        // Cholesky with reciprocal diagonal
        float L[6][6], dinv[6];
        #pragma unroll
        for (int i = 0; i < 6; ++i) {
            #pragma unroll
            for (int j = 0; j < 6; ++j) {
                if (j > i) continue;
                float sum = Hm[i][j];
                #pragma unroll
                for (int k2 = 0; k2 < 6; ++k2)
                    if (k2 < j) sum -= L[i][k2] * L[j][k2];
                if (i == j) { L[i][i] = sqrtf(sum); dinv[i] = 1.0f / L[i][i]; }
                else        L[i][j] = sum * dinv[j];
            }
        }
        float z[6];
        #pragma unroll
        for (int i = 0; i < 6; ++i) {
            float sum = rhs[i];
            #pragma unroll
            for (int k2 = 0; k2 < 6; ++k2)
                if (k2 < i) sum -= L[i][k2] * z[k2];
            z[i] = sum * dinv[i];
        }
        float y[6];
        #pragma unroll
        for (int i = 5; i >= 0; --i) {
            float sum = z[i];
            #pragma unroll
            for (int k2 = 0; k2 < 6; ++k2)
                if (k2 > i) sum -= L[k2][i] * y[k2];
            y[i] = sum * dinv[i];
        }

        float drx = Rm[0][0]*y[0] + Rm[1][0]*y[1] + Rm[2][0]*y[2];
        float dry = Rm[0][1]*y[0] + Rm[1][1]*y[1] + Rm[2][1]*y[2];
        float drz = Rm[0][2]*y[0] + Rm[1][2]*y[1] + Rm[2][2]*y[2];
        float dpx = Rm[0][0]*y[3] + Rm[1][0]*y[4] + Rm[2][0]*y[5];
        float dpy = Rm[0][1]*y[3] + Rm[1][1]*y[4] + Rm[2][1]*y[5];
        float dpz = Rm[0][2]*y[3] + Rm[1][2]*y[4] + Rm[2][2]*y[5];

        float th2  = dpx*dpx + dpy*dpy + dpz*dpz;
        bool  sm   = th2 < 1e-12f;
        float th2s = sm ? 1.0f : th2;
        float th   = sqrtf(th2s);
        float sth  = __sinf(th), cth = __cosf(th);
        float it2  = 1.0f / th2s;
        float Ae = sm ? 1.0f : sth / th;
        float Be = sm ? 0.5f : (1.0f - cth) * it2;
        float Ce = sm ? (1.0f / 6.0f) : (th - sth) * it2 / th;
        float Rd00 = 1.0f + Be * (dpx*dpx - th2);
        float Rd01 = -Ae * dpz + Be * dpx * dpy;
        float Rd02 =  Ae * dpy + Be * dpx * dpz;
        float Rd10 =  Ae * dpz + Be * dpx * dpy;
        float Rd11 = 1.0f + Be * (dpy*dpy - th2);
        float Rd12 = -Ae * dpx + Be * dpy * dpz;
        float Rd20 = -Ae * dpy + Be * dpx * dpz;
        float Rd21 =  Ae * dpx + Be * dpy * dpz;
        float Rd22 = 1.0f + Be * (dpz*dpz - th2);
        float V00 = 1.0f + Ce * (dpx*dpx - th2);
        float V01 = -Be * dpz + Ce * dpx * dpy;
        float V02 =  Be * dpy + Ce * dpx * dpz;
        float V10 =  Be * dpz + Ce * dpx * dpy;
        float V11 = 1.0f + Ce * (dpy*dpy - th2);
        float V12 = -Be * dpx + Ce * dpy * dpz;
        float V20 = -Be * dpy + Ce * dpx * dpz;
        float V21 =  Be * dpx + Ce * dpy * dpz;
        float V22 = 1.0f + Ce * (dpz*dpz - th2);
        float tdx = V00 * drx + V01 * dry + V02 * drz;
        float tdy = V10 * drx + V11 * dry + V12 * drz;
        float tdz = V20 * drx + V21 * dry + V22 * drz;

        float nR[3][3];
        nR[0][0] = Rm[0][0]*Rd00 + Rm[0][1]*Rd10 + Rm[0][2]*Rd20;
        nR[0][1] = Rm[0][0]*Rd01 + Rm[0][1]*Rd11 + Rm[0][2]*Rd21;
        nR[0][2] = Rm[0][0]*Rd02 + Rm[0][1]*Rd12 + Rm[0][2]*Rd22;
        nR[1][0] = Rm[1][0]*Rd00 + Rm[1][1]*Rd10 + Rm[1][2]*Rd20;
        nR[1][1] = Rm[1][0]*Rd01 + Rm[1][1]*Rd11 + Rm[1][2]*Rd21;
        nR[1][2] = Rm[1][0]*Rd02 + Rm[1][1]*Rd12 + Rm[1][2]*Rd22;
        nR[2][0] = Rm[2][0]*Rd00 + Rm[2][1]*Rd10 + Rm[2][2]*Rd20;
        nR[2][1] = Rm[2][0]*Rd01 + Rm[2][1]*Rd11 + Rm[2][2]*Rd21;
        nR[2][2] = Rm[2][0]*Rd02 + Rm[2][1]*Rd12 + Rm[2][2]*Rd22;
        float ntx = Rm[0][0]*tdx + Rm[0][1]*tdy + Rm[0][2]*tdz + tv[0];
        float nty = Rm[1][0]*tdx + Rm[1][1]*tdy + Rm[1][2]*tdz + tv[1];
        float ntz = Rm[2][0]*tdx + Rm[2][1]*tdy + Rm[2][2]*tdz + tv[2];
        #pragma unroll
        for (int i = 0; i < 3; ++i)
            #pragma unroll
            for (int j = 0; j < 3; ++j) Rm[i][j] = nR[i][j];
        tv[0] = ntx; tv[1] = nty; tv[2] = ntz;
    }

    // epilogue: Out = inv(Tsv) * T * Tsv  (lane 0 writes)
    if (lane == 0) {
        float R00 = Rm[0][0], R01 = Rm[0][1], R02 = Rm[0][2];
        float R10 = Rm[1][0], R11 = Rm[1][1], R12 = Rm[1][2];
        float R20 = Rm[2][0], R21 = Rm[2][1], R22 = Rm[2][2];
        float tx = tv[0], ty = tv[1], tz = tv[2];

        float Rv00 = Tsv[0], Rv01 = Tsv[1], Rv02 = Tsv[2],  tvx = Tsv[3];
        float Rv10 = Tsv[4], Rv11 = Tsv[5], Rv12 = Tsv[6],  tvy = Tsv[7];
        float Rv20 = Tsv[8], Rv21 = Tsv[9], Rv22 = Tsv[10], tvz = Tsv[11];

        float P00 = R00*Rv00 + R01*Rv10 + R02*Rv20;
        float P01 = R00*Rv01 + R01*Rv11 + R02*Rv21;
        float P02 = R00*Rv02 + R01*Rv12 + R02*Rv22;
        float P10 = R10*Rv00 + R11*Rv10 + R12*Rv20;
        float P11 = R10*Rv01 + R11*Rv11 + R12*Rv21;
        float P12 = R10*Rv02 + R11*Rv12 + R12*Rv22;
        float P20 = R20*Rv00 + R21*Rv10 + R22*Rv20;
        float P21 = R20*Rv01 + R21*Rv11 + R22*Rv21;
        float P22 = R20*Rv02 + R21*Rv12 + R22*Rv22;
        float Ptx = R00*tvx + R01*tvy + R02*tvz + tx;
        float Pty = R10*tvx + R11*tvy + R12*tvz + ty;
        float Ptz = R20*tvx + R21*tvy + R22*tvz + tz;

        float ex = Ptx - tvx, ey = Pty - tvy, ez = Ptz - tvz;
        float* o = out + (size_t)b * 16;
        o[0]  = Rv00*P00 + Rv10*P10 + Rv20*P20;
        o[1]  = Rv00*P01 + Rv10*P11 + Rv20*P21;
        o[2]  = Rv00*P02 + Rv10*P12 + Rv20*P22;
        o[3]  = Rv00*ex  + Rv10*ey  + Rv20*ez;
        o[4]  = Rv01*P00 + Rv11*P10 + Rv21*P20;
        o[5]  = Rv01*P01 + Rv11*P11 + Rv21*P21;
        o[6]  = Rv01*P02 + Rv11*P12 + Rv21*P22;
        o[7]  = Rv01*ex  + Rv11*ey  + Rv21*ez;
        o[8]  = Rv02*P00 + Rv12*P10 + Rv22*P20;
        o[9]  = Rv02*P01 + Rv12*P11 + Rv22*P21;
        o[10] = Rv02*P02 + Rv12*P12 + Rv22*P22;
        o[11] = Rv02*ex  + Rv12*ey  + Rv22*ez;
        o[12] = 0.0f; o[13] = 0.0f; o[14] = 0.0f; o[15] = 1.0f;
    }
}

extern "C" void kernel_launch(void* const* d_in, const int* in_sizes, int n_in,
                              void* d_out, int out_size, void* d_ws, size_t ws_size,
                              hipStream_t stream)
{
    const float* src4  = (const float*)d_in[0];
    const float* trg4  = (const float*)d_in[1];
    const float* wts   = (const float*)d_in[2];
    const float* Tinit = (const float*)d_in[3];
    const float* icov  = (const float*)d_in[4];
    const float* Tsv   = (const float*)d_in[5];

    const int B = in_sizes[3] / 16;   // T_trg_src_init is (B,4,4)

    hipLaunchKernelGGL(lie_gn_fused, dim3(B), dim3(BDIM), 0, stream,
                       src4, trg4, wts, Tinit, icov, Tsv, (float*)d_out);
}